// Round 1
// baseline (10774.766 us; speedup 1.0000x reference)
//
#include <hip/hip_runtime.h>

#define N_NODES 100000
#define N_EDGES 3200000
#define D 256

// ---------------------------------------------------------------------------
// Kernel 1: edge-parallel scatter-add.  One wave (64 lanes) per edge; each
// lane handles a float4 chunk of the 256-wide feature row.
// support[row] += val * x[col]   (support lives in d_out, pre-zeroed)
// ---------------------------------------------------------------------------
__global__ __launch_bounds__(256) void scatter_kernel(
    const float* __restrict__ x,
    const int* __restrict__ erow,
    const int* __restrict__ ecol,
    const float* __restrict__ eval_,
    float* __restrict__ support,
    int nwaves) {
  int lane = threadIdx.x & 63;
  int wave = __builtin_amdgcn_readfirstlane(
      (int)((blockIdx.x * blockDim.x + threadIdx.x) >> 6));

  for (int e = wave; e < N_EDGES; e += nwaves) {
    int r = erow[e];
    int c = ecol[e];
    float v = eval_[e];
    const float4* xr = (const float4*)(x + (size_t)c * D);
    float4 xv = xr[lane];
    float* dst = support + (size_t)r * D + lane * 4;
    atomicAdd(dst + 0, v * xv.x);
    atomicAdd(dst + 1, v * xv.y);
    atomicAdd(dst + 2, v * xv.z);
    atomicAdd(dst + 3, v * xv.w);
  }
}

// ---------------------------------------------------------------------------
// Kernel 2: out = relu(support @ W), IN PLACE over d_out.
// Each block owns 32 rows: stage them in LDS, then compute & overwrite.
// Thread layout: 256 threads = 64 col-groups (float4 of W) x 4 row-groups of 8.
// Per k: 1 coalesced float4 load of W row, 8 LDS broadcast reads, 32 FMAs.
// ---------------------------------------------------------------------------
__global__ __launch_bounds__(256) void gemm_relu_inplace(
    const float* __restrict__ W, float* __restrict__ io) {
  __shared__ float s[32][D];
  const int tid = threadIdx.x;
  const int row0 = blockIdx.x * 32;

  // Stage 32 rows of support into LDS (float4, coalesced).
  {
    const float4* src = (const float4*)(io + (size_t)row0 * D);
    float4* sd = (float4*)&s[0][0];
    #pragma unroll
    for (int t = 0; t < 8; ++t) sd[tid + t * 256] = src[tid + t * 256];
  }
  __syncthreads();

  const int j0 = (tid & 63) * 4;       // column group (float4)
  const int i0 = (tid >> 6) * 8;       // row group (wave-uniform)

  float acc[8][4];
  #pragma unroll
  for (int i = 0; i < 8; ++i)
    for (int q = 0; q < 4; ++q) acc[i][q] = 0.f;

  #pragma unroll 4
  for (int k = 0; k < D; ++k) {
    float4 w4 = *(const float4*)(W + (size_t)k * D + j0);
    #pragma unroll
    for (int i = 0; i < 8; ++i) {
      float sv = s[i0 + i][k];  // wave-uniform address -> LDS broadcast
      acc[i][0] = fmaf(sv, w4.x, acc[i][0]);
      acc[i][1] = fmaf(sv, w4.y, acc[i][1]);
      acc[i][2] = fmaf(sv, w4.z, acc[i][2]);
      acc[i][3] = fmaf(sv, w4.w, acc[i][3]);
    }
  }

  #pragma unroll
  for (int i = 0; i < 8; ++i) {
    float4 o;
    o.x = fmaxf(acc[i][0], 0.f);
    o.y = fmaxf(acc[i][1], 0.f);
    o.z = fmaxf(acc[i][2], 0.f);
    o.w = fmaxf(acc[i][3], 0.f);
    *(float4*)(io + (size_t)(row0 + i0 + i) * D + j0) = o;
  }
}

extern "C" void kernel_launch(void* const* d_in, const int* in_sizes, int n_in,
                              void* d_out, int out_size, void* d_ws, size_t ws_size,
                              hipStream_t stream) {
  const float* x     = (const float*)d_in[0];
  const int*   erow  = (const int*)d_in[1];
  const int*   ecol  = (const int*)d_in[2];
  const float* eval_ = (const float*)d_in[3];
  const float* W     = (const float*)d_in[4];
  float* out = (float*)d_out;

  // Zero the support/output accumulator.
  hipMemsetAsync(out, 0, (size_t)N_NODES * D * sizeof(float), stream);

  // Phase 1: support = P @ X via atomic scatter (support in d_out).
  const int blocks = 2048;                       // 8192 waves, ~391 edges each
  const int nwaves = blocks * (256 / 64);
  scatter_kernel<<<blocks, 256, 0, stream>>>(x, erow, ecol, eval_, out, nwaves);

  // Phase 2: out = relu(support @ W), in place (each block owns its 32 rows).
  gemm_relu_inplace<<<N_NODES / 32, 256, 0, stream>>>(W, out);
}

// Round 2
// 1152.123 us; speedup vs baseline: 9.3521x; 9.3521x over previous
//
#include <hip/hip_runtime.h>

#define N_NODES 100000
#define N_EDGES 3200000
#define D 256

// ===========================================================================
// CSR-build path: histogram -> scan -> sort-scatter -> per-row accumulate.
// ===========================================================================

// K1: histogram of destination rows.
__global__ __launch_bounds__(256) void hist_kernel(
    const int* __restrict__ erow, int* __restrict__ cnt) {
  int stride = gridDim.x * blockDim.x;
  for (int e = blockIdx.x * blockDim.x + threadIdx.x; e < N_EDGES; e += stride)
    atomicAdd(&cnt[erow[e]], 1);
}

// K2: exclusive scan of cnt -> row_ptr (single block), and zero cnt for reuse
// as the scatter cursor.
__global__ __launch_bounds__(1024) void scan_kernel(
    int* __restrict__ cnt, int* __restrict__ row_ptr) {
  __shared__ int partial[1024];
  const int T = 1024;
  const int per = (N_NODES + T - 1) / T;  // 98
  int tid = threadIdx.x;
  int base = tid * per;

  int sum = 0;
  for (int i = 0; i < per; ++i) {
    int idx = base + i;
    if (idx < N_NODES) sum += cnt[idx];
  }
  partial[tid] = sum;
  __syncthreads();
  for (int off = 1; off < T; off <<= 1) {
    int v = (tid >= off) ? partial[tid - off] : 0;
    __syncthreads();
    partial[tid] += v;
    __syncthreads();
  }
  int run = (tid == 0) ? 0 : partial[tid - 1];
  for (int i = 0; i < per; ++i) {
    int idx = base + i;
    if (idx < N_NODES) {
      row_ptr[idx] = run;
      run += cnt[idx];
      cnt[idx] = 0;  // becomes the cursor
    }
  }
  if (tid == T - 1) row_ptr[N_NODES] = run;
}

// K3: scatter edges into row-sorted order: sorted[pos] = {col, val_bits}.
__global__ __launch_bounds__(256) void sort_scatter_kernel(
    const int* __restrict__ erow, const int* __restrict__ ecol,
    const float* __restrict__ eval_, const int* __restrict__ row_ptr,
    int* __restrict__ cursor, int2* __restrict__ sorted) {
  int e = blockIdx.x * blockDim.x + threadIdx.x;
  if (e >= N_EDGES) return;
  int r = erow[e];
  int pos = row_ptr[r] + atomicAdd(&cursor[r], 1);
  sorted[pos] = make_int2(ecol[e], __float_as_int(eval_[e]));
}

// K4: one wave per row; float4-per-lane register accumulator.
__global__ __launch_bounds__(256) void row_accum_kernel(
    const float* __restrict__ x, const int2* __restrict__ sorted,
    const int* __restrict__ row_ptr, float* __restrict__ support) {
  int lane = threadIdx.x & 63;
  int r = (int)((blockIdx.x * blockDim.x + threadIdx.x) >> 6);
  if (r >= N_NODES) return;
  int beg = row_ptr[r];
  int end = row_ptr[r + 1];
  const float4* __restrict__ x4 = (const float4*)x;
  float4 acc = make_float4(0.f, 0.f, 0.f, 0.f);

  int p = beg;
  for (; p + 1 < end; p += 2) {
    int2 cv0 = sorted[p];
    int2 cv1 = sorted[p + 1];
    float4 xv0 = x4[(size_t)cv0.x * 64 + lane];
    float4 xv1 = x4[(size_t)cv1.x * 64 + lane];
    float v0 = __int_as_float(cv0.y);
    float v1 = __int_as_float(cv1.y);
    acc.x = fmaf(v0, xv0.x, acc.x);
    acc.y = fmaf(v0, xv0.y, acc.y);
    acc.z = fmaf(v0, xv0.z, acc.z);
    acc.w = fmaf(v0, xv0.w, acc.w);
    acc.x = fmaf(v1, xv1.x, acc.x);
    acc.y = fmaf(v1, xv1.y, acc.y);
    acc.z = fmaf(v1, xv1.z, acc.z);
    acc.w = fmaf(v1, xv1.w, acc.w);
  }
  if (p < end) {
    int2 cv = sorted[p];
    float v = __int_as_float(cv.y);
    float4 xv = x4[(size_t)cv.x * 64 + lane];
    acc.x = fmaf(v, xv.x, acc.x);
    acc.y = fmaf(v, xv.y, acc.y);
    acc.z = fmaf(v, xv.z, acc.z);
    acc.w = fmaf(v, xv.w, acc.w);
  }
  ((float4*)support)[(size_t)r * 64 + lane] = acc;
}

// ===========================================================================
// Fallback (round-0): edge-parallel atomic scatter. Used only if ws too small.
// ===========================================================================
__global__ __launch_bounds__(256) void scatter_kernel(
    const float* __restrict__ x, const int* __restrict__ erow,
    const int* __restrict__ ecol, const float* __restrict__ eval_,
    float* __restrict__ support, int nwaves) {
  int lane = threadIdx.x & 63;
  int wave = __builtin_amdgcn_readfirstlane(
      (int)((blockIdx.x * blockDim.x + threadIdx.x) >> 6));
  for (int e = wave; e < N_EDGES; e += nwaves) {
    int r = erow[e];
    int c = ecol[e];
    float v = eval_[e];
    float4 xv = ((const float4*)(x + (size_t)c * D))[lane];
    float* dst = support + (size_t)r * D + lane * 4;
    atomicAdd(dst + 0, v * xv.x);
    atomicAdd(dst + 1, v * xv.y);
    atomicAdd(dst + 2, v * xv.z);
    atomicAdd(dst + 3, v * xv.w);
  }
}

// ===========================================================================
// GEMM: out = relu(support @ W), in place over d_out (each block owns 32 rows).
// ===========================================================================
__global__ __launch_bounds__(256) void gemm_relu_inplace(
    const float* __restrict__ W, float* __restrict__ io) {
  __shared__ float s[32][D];
  const int tid = threadIdx.x;
  const int row0 = blockIdx.x * 32;

  {
    const float4* src = (const float4*)(io + (size_t)row0 * D);
    float4* sd = (float4*)&s[0][0];
    #pragma unroll
    for (int t = 0; t < 8; ++t) sd[tid + t * 256] = src[tid + t * 256];
  }
  __syncthreads();

  const int j0 = (tid & 63) * 4;
  const int i0 = (tid >> 6) * 8;

  float acc[8][4];
  #pragma unroll
  for (int i = 0; i < 8; ++i)
    for (int q = 0; q < 4; ++q) acc[i][q] = 0.f;

  #pragma unroll 4
  for (int k = 0; k < D; ++k) {
    float4 w4 = *(const float4*)(W + (size_t)k * D + j0);
    #pragma unroll
    for (int i = 0; i < 8; ++i) {
      float sv = s[i0 + i][k];
      acc[i][0] = fmaf(sv, w4.x, acc[i][0]);
      acc[i][1] = fmaf(sv, w4.y, acc[i][1]);
      acc[i][2] = fmaf(sv, w4.z, acc[i][2]);
      acc[i][3] = fmaf(sv, w4.w, acc[i][3]);
    }
  }

  #pragma unroll
  for (int i = 0; i < 8; ++i) {
    float4 o;
    o.x = fmaxf(acc[i][0], 0.f);
    o.y = fmaxf(acc[i][1], 0.f);
    o.z = fmaxf(acc[i][2], 0.f);
    o.w = fmaxf(acc[i][3], 0.f);
    *(float4*)(io + (size_t)(row0 + i0 + i) * D + j0) = o;
  }
}

extern "C" void kernel_launch(void* const* d_in, const int* in_sizes, int n_in,
                              void* d_out, int out_size, void* d_ws, size_t ws_size,
                              hipStream_t stream) {
  const float* x     = (const float*)d_in[0];
  const int*   erow  = (const int*)d_in[1];
  const int*   ecol  = (const int*)d_in[2];
  const float* eval_ = (const float*)d_in[3];
  const float* W     = (const float*)d_in[4];
  float* out = (float*)d_out;

  // Workspace layout.
  const size_t cnt_bytes    = (size_t)N_NODES * sizeof(int);        // 400 KB
  const size_t rp_bytes     = (size_t)(N_NODES + 1) * sizeof(int);  // 400 KB
  const size_t sorted_off   = ((cnt_bytes + rp_bytes + 15) / 16) * 16;
  const size_t need         = sorted_off + (size_t)N_EDGES * 8;     // ~26.4 MB

  if (ws_size >= need) {
    int*  cnt     = (int*)d_ws;
    int*  row_ptr = (int*)((char*)d_ws + cnt_bytes);
    int2* sorted  = (int2*)((char*)d_ws + sorted_off);

    hipMemsetAsync(cnt, 0, cnt_bytes, stream);
    hist_kernel<<<2048, 256, 0, stream>>>(erow, cnt);
    scan_kernel<<<1, 1024, 0, stream>>>(cnt, row_ptr);
    sort_scatter_kernel<<<(N_EDGES + 255) / 256, 256, 0, stream>>>(
        erow, ecol, eval_, row_ptr, cnt, sorted);
    row_accum_kernel<<<(N_NODES * 64 + 255) / 256, 256, 0, stream>>>(
        x, sorted, row_ptr, out);
  } else {
    // Fallback: atomic scatter into pre-zeroed d_out.
    hipMemsetAsync(out, 0, (size_t)N_NODES * D * sizeof(float), stream);
    const int blocks = 2048;
    const int nwaves = blocks * (256 / 64);
    scatter_kernel<<<blocks, 256, 0, stream>>>(x, erow, ecol, eval_, out, nwaves);
  }

  // Phase 2: out = relu(support @ W), in place.
  gemm_relu_inplace<<<N_NODES / 32, 256, 0, stream>>>(W, out);
}

// Round 3
// 903.179 us; speedup vs baseline: 11.9298x; 1.2756x over previous
//
#include <hip/hip_runtime.h>

#define N_NODES 100000
#define N_EDGES 3200000
#define D 256

typedef __attribute__((ext_vector_type(8))) short short8;
typedef __attribute__((ext_vector_type(4))) float f32x4;

static __device__ __forceinline__ unsigned short f2bf(float f) {
  unsigned u = __float_as_uint(f);
  u += 0x7FFF + ((u >> 16) & 1);     // round-to-nearest-even
  return (unsigned short)(u >> 16);
}
static __device__ __forceinline__ float bf2f(unsigned short h) {
  return __uint_as_float(((unsigned)h) << 16);
}

// ===========================================================================
// CSR build (shared by both CSR paths)
// ===========================================================================
__global__ __launch_bounds__(256) void hist_kernel(
    const int* __restrict__ erow, int* __restrict__ cnt) {
  int stride = gridDim.x * blockDim.x;
  for (int e = blockIdx.x * blockDim.x + threadIdx.x; e < N_EDGES; e += stride)
    atomicAdd(&cnt[erow[e]], 1);
}

__global__ __launch_bounds__(1024) void scan_kernel(
    int* __restrict__ cnt, int* __restrict__ row_ptr) {
  __shared__ int partial[1024];
  const int T = 1024;
  const int per = (N_NODES + T - 1) / T;
  int tid = threadIdx.x;
  int base = tid * per;
  int sum = 0;
  for (int i = 0; i < per; ++i) {
    int idx = base + i;
    if (idx < N_NODES) sum += cnt[idx];
  }
  partial[tid] = sum;
  __syncthreads();
  for (int off = 1; off < T; off <<= 1) {
    int v = (tid >= off) ? partial[tid - off] : 0;
    __syncthreads();
    partial[tid] += v;
    __syncthreads();
  }
  int run = (tid == 0) ? 0 : partial[tid - 1];
  for (int i = 0; i < per; ++i) {
    int idx = base + i;
    if (idx < N_NODES) {
      row_ptr[idx] = run;
      run += cnt[idx];
      cnt[idx] = 0;
    }
  }
  if (tid == T - 1) row_ptr[N_NODES] = run;
}

__global__ __launch_bounds__(256) void sort_scatter_kernel(
    const int* __restrict__ erow, const int* __restrict__ ecol,
    const float* __restrict__ eval_, const int* __restrict__ row_ptr,
    int* __restrict__ cursor, int2* __restrict__ sorted) {
  int e = blockIdx.x * blockDim.x + threadIdx.x;
  if (e >= N_EDGES) return;
  int r = erow[e];
  int pos = row_ptr[r] + atomicAdd(&cursor[r], 1);
  sorted[pos] = make_int2(ecol[e], __float_as_int(eval_[e]));
}

// ===========================================================================
// Path A: bf16 gathers + bf16 MFMA GEMM
// ===========================================================================
__global__ __launch_bounds__(256) void convert_x(
    const float4* __restrict__ xf, ushort* __restrict__ xb) {
  int i = blockIdx.x * 256 + threadIdx.x;  // one float4 (4 elems) per thread
  float4 v = xf[i];
  ushort4 o;
  o.x = f2bf(v.x); o.y = f2bf(v.y); o.z = f2bf(v.z); o.w = f2bf(v.w);
  *(ushort4*)(xb + (size_t)i * 4) = o;
}

// wt[n][k] = bf16(W[k][n]); one wave per output row n.
__global__ __launch_bounds__(64) void convert_wt(
    const float* __restrict__ W, ushort* __restrict__ wt) {
  int n = blockIdx.x;
  int k0 = threadIdx.x * 4;
  ushort4 o;
  o.x = f2bf(W[(size_t)(k0 + 0) * D + n]);
  o.y = f2bf(W[(size_t)(k0 + 1) * D + n]);
  o.z = f2bf(W[(size_t)(k0 + 2) * D + n]);
  o.w = f2bf(W[(size_t)(k0 + 3) * D + n]);
  *(ushort4*)(wt + (size_t)n * D + k0) = o;
}

// One wave per row; 4-edge unroll, 4 independent bf16 gathers in flight.
__global__ __launch_bounds__(256) void row_accum_bf16(
    const ushort* __restrict__ xb, const int2* __restrict__ sorted,
    const int* __restrict__ row_ptr, ushort* __restrict__ sup) {
  int lane = threadIdx.x & 63;
  int r = (int)((blockIdx.x << 2) + (threadIdx.x >> 6));
  r = __builtin_amdgcn_readfirstlane(r);
  if (r >= N_NODES) return;
  int beg = row_ptr[r];
  int end = row_ptr[r + 1];
  float4 acc = make_float4(0.f, 0.f, 0.f, 0.f);
  const int lo = lane * 4;

  int p = beg;
  // align to even entry so int4 loads are 16B-aligned
  if ((p & 1) && p < end) {
    int2 cv = sorted[p];
    float v = __int_as_float(cv.y);
    ushort4 g = *(const ushort4*)(xb + (size_t)cv.x * D + lo);
    acc.x = fmaf(v, bf2f(g.x), acc.x);
    acc.y = fmaf(v, bf2f(g.y), acc.y);
    acc.z = fmaf(v, bf2f(g.z), acc.z);
    acc.w = fmaf(v, bf2f(g.w), acc.w);
    ++p;
  }
  for (; p + 4 <= end; p += 4) {
    int4 e01 = *(const int4*)(sorted + p);
    int4 e23 = *(const int4*)(sorted + p + 2);
    ushort4 g0 = *(const ushort4*)(xb + (size_t)e01.x * D + lo);
    ushort4 g1 = *(const ushort4*)(xb + (size_t)e01.z * D + lo);
    ushort4 g2 = *(const ushort4*)(xb + (size_t)e23.x * D + lo);
    ushort4 g3 = *(const ushort4*)(xb + (size_t)e23.z * D + lo);
    float v0 = __int_as_float(e01.y);
    float v1 = __int_as_float(e01.w);
    float v2 = __int_as_float(e23.y);
    float v3 = __int_as_float(e23.w);
    acc.x = fmaf(v0, bf2f(g0.x), acc.x);
    acc.y = fmaf(v0, bf2f(g0.y), acc.y);
    acc.z = fmaf(v0, bf2f(g0.z), acc.z);
    acc.w = fmaf(v0, bf2f(g0.w), acc.w);
    acc.x = fmaf(v1, bf2f(g1.x), acc.x);
    acc.y = fmaf(v1, bf2f(g1.y), acc.y);
    acc.z = fmaf(v1, bf2f(g1.z), acc.z);
    acc.w = fmaf(v1, bf2f(g1.w), acc.w);
    acc.x = fmaf(v2, bf2f(g2.x), acc.x);
    acc.y = fmaf(v2, bf2f(g2.y), acc.y);
    acc.z = fmaf(v2, bf2f(g2.z), acc.z);
    acc.w = fmaf(v2, bf2f(g2.w), acc.w);
    acc.x = fmaf(v3, bf2f(g3.x), acc.x);
    acc.y = fmaf(v3, bf2f(g3.y), acc.y);
    acc.z = fmaf(v3, bf2f(g3.z), acc.z);
    acc.w = fmaf(v3, bf2f(g3.w), acc.w);
  }
  for (; p < end; ++p) {
    int2 cv = sorted[p];
    float v = __int_as_float(cv.y);
    ushort4 g = *(const ushort4*)(xb + (size_t)cv.x * D + lo);
    acc.x = fmaf(v, bf2f(g.x), acc.x);
    acc.y = fmaf(v, bf2f(g.y), acc.y);
    acc.z = fmaf(v, bf2f(g.z), acc.z);
    acc.w = fmaf(v, bf2f(g.w), acc.w);
  }
  ushort4 o;
  o.x = f2bf(acc.x); o.y = f2bf(acc.y); o.z = f2bf(acc.z); o.w = f2bf(acc.w);
  *(ushort4*)(sup + (size_t)r * D + lo) = o;
}

// out = relu(sup @ wt^T) with sup[M][K] bf16, wt[N][K] bf16 (pre-transposed W).
// Block: 256 thr = 4 waves; block tile 64(M) x 256(N); wave owns 64 N-cols.
// mfma_f32_16x16x32_bf16: A/B frag = row (lane&15), k = (lane>>4)*8 + j (16B);
// C/D: col = lane&15, row = (lane>>4)*4 + j.
__global__ __launch_bounds__(256) void mfma_gemm_relu(
    const ushort* __restrict__ sup, const ushort* __restrict__ wt,
    float* __restrict__ out) {
  const int lane = threadIdx.x & 63;
  const int wave = threadIdx.x >> 6;
  const int m0 = blockIdx.x * 64;
  const int n0 = wave * 64;
  const int lrow = lane & 15;
  const int kch = (lane >> 4) * 8;

  f32x4 acc[4][4];
  #pragma unroll
  for (int i = 0; i < 4; ++i)
    #pragma unroll
    for (int j = 0; j < 4; ++j)
      acc[i][j] = (f32x4){0.f, 0.f, 0.f, 0.f};

  const ushort* sa = sup + (size_t)(m0 + lrow) * D + kch;
  const ushort* sb = wt + (size_t)(n0 + lrow) * D + kch;

  #pragma unroll
  for (int ks = 0; ks < 8; ++ks) {
    short8 a[4], b[4];
    #pragma unroll
    for (int i = 0; i < 4; ++i) {
      a[i] = *(const short8*)(sa + (size_t)i * 16 * D + ks * 32);
      b[i] = *(const short8*)(sb + (size_t)i * 16 * D + ks * 32);
    }
    #pragma unroll
    for (int mi = 0; mi < 4; ++mi)
      #pragma unroll
      for (int ni = 0; ni < 4; ++ni)
        acc[mi][ni] = __builtin_amdgcn_mfma_f32_16x16x32_bf16(
            a[mi], b[ni], acc[mi][ni], 0, 0, 0);
  }

  #pragma unroll
  for (int mi = 0; mi < 4; ++mi) {
    int rbase = m0 + mi * 16 + (lane >> 4) * 4;
    #pragma unroll
    for (int ni = 0; ni < 4; ++ni) {
      int col = n0 + ni * 16 + lrow;
      #pragma unroll
      for (int j = 0; j < 4; ++j) {
        int row = rbase + j;
        if (row < N_NODES)
          out[(size_t)row * D + col] = fmaxf(acc[mi][ni][j], 0.f);
      }
    }
  }
}

// ===========================================================================
// Path B: f32 row-accum + f32 VALU GEMM (proven round-2 path)
// ===========================================================================
__global__ __launch_bounds__(256) void row_accum_kernel(
    const float* __restrict__ x, const int2* __restrict__ sorted,
    const int* __restrict__ row_ptr, float* __restrict__ support) {
  int lane = threadIdx.x & 63;
  int r = (int)((blockIdx.x * blockDim.x + threadIdx.x) >> 6);
  if (r >= N_NODES) return;
  int beg = row_ptr[r];
  int end = row_ptr[r + 1];
  const float4* __restrict__ x4 = (const float4*)x;
  float4 acc = make_float4(0.f, 0.f, 0.f, 0.f);
  int p = beg;
  for (; p + 1 < end; p += 2) {
    int2 cv0 = sorted[p];
    int2 cv1 = sorted[p + 1];
    float4 xv0 = x4[(size_t)cv0.x * 64 + lane];
    float4 xv1 = x4[(size_t)cv1.x * 64 + lane];
    float v0 = __int_as_float(cv0.y);
    float v1 = __int_as_float(cv1.y);
    acc.x = fmaf(v0, xv0.x, acc.x);
    acc.y = fmaf(v0, xv0.y, acc.y);
    acc.z = fmaf(v0, xv0.z, acc.z);
    acc.w = fmaf(v0, xv0.w, acc.w);
    acc.x = fmaf(v1, xv1.x, acc.x);
    acc.y = fmaf(v1, xv1.y, acc.y);
    acc.z = fmaf(v1, xv1.z, acc.z);
    acc.w = fmaf(v1, xv1.w, acc.w);
  }
  if (p < end) {
    int2 cv = sorted[p];
    float v = __int_as_float(cv.y);
    float4 xv = x4[(size_t)cv.x * 64 + lane];
    acc.x = fmaf(v, xv.x, acc.x);
    acc.y = fmaf(v, xv.y, acc.y);
    acc.z = fmaf(v, xv.z, acc.z);
    acc.w = fmaf(v, xv.w, acc.w);
  }
  ((float4*)support)[(size_t)r * 64 + lane] = acc;
}

__global__ __launch_bounds__(256) void scatter_kernel(
    const float* __restrict__ x, const int* __restrict__ erow,
    const int* __restrict__ ecol, const float* __restrict__ eval_,
    float* __restrict__ support, int nwaves) {
  int lane = threadIdx.x & 63;
  int wave = __builtin_amdgcn_readfirstlane(
      (int)((blockIdx.x * blockDim.x + threadIdx.x) >> 6));
  for (int e = wave; e < N_EDGES; e += nwaves) {
    int r = erow[e];
    int c = ecol[e];
    float v = eval_[e];
    float4 xv = ((const float4*)(x + (size_t)c * D))[lane];
    float* dst = support + (size_t)r * D + lane * 4;
    atomicAdd(dst + 0, v * xv.x);
    atomicAdd(dst + 1, v * xv.y);
    atomicAdd(dst + 2, v * xv.z);
    atomicAdd(dst + 3, v * xv.w);
  }
}

__global__ __launch_bounds__(256) void gemm_relu_inplace(
    const float* __restrict__ W, float* __restrict__ io) {
  __shared__ float s[32][D];
  const int tid = threadIdx.x;
  const int row0 = blockIdx.x * 32;
  {
    const float4* src = (const float4*)(io + (size_t)row0 * D);
    float4* sd = (float4*)&s[0][0];
    #pragma unroll
    for (int t = 0; t < 8; ++t) sd[tid + t * 256] = src[tid + t * 256];
  }
  __syncthreads();
  const int j0 = (tid & 63) * 4;
  const int i0 = (tid >> 6) * 8;
  float acc[8][4];
  #pragma unroll
  for (int i = 0; i < 8; ++i)
    for (int q = 0; q < 4; ++q) acc[i][q] = 0.f;
  #pragma unroll 4
  for (int k = 0; k < D; ++k) {
    float4 w4 = *(const float4*)(W + (size_t)k * D + j0);
    #pragma unroll
    for (int i = 0; i < 8; ++i) {
      float sv = s[i0 + i][k];
      acc[i][0] = fmaf(sv, w4.x, acc[i][0]);
      acc[i][1] = fmaf(sv, w4.y, acc[i][1]);
      acc[i][2] = fmaf(sv, w4.z, acc[i][2]);
      acc[i][3] = fmaf(sv, w4.w, acc[i][3]);
    }
  }
  #pragma unroll
  for (int i = 0; i < 8; ++i) {
    float4 o;
    o.x = fmaxf(acc[i][0], 0.f);
    o.y = fmaxf(acc[i][1], 0.f);
    o.z = fmaxf(acc[i][2], 0.f);
    o.w = fmaxf(acc[i][3], 0.f);
    *(float4*)(io + (size_t)(row0 + i0 + i) * D + j0) = o;
  }
}

extern "C" void kernel_launch(void* const* d_in, const int* in_sizes, int n_in,
                              void* d_out, int out_size, void* d_ws, size_t ws_size,
                              hipStream_t stream) {
  const float* x     = (const float*)d_in[0];
  const int*   erow  = (const int*)d_in[1];
  const int*   ecol  = (const int*)d_in[2];
  const float* eval_ = (const float*)d_in[3];
  const float* W     = (const float*)d_in[4];
  float* out = (float*)d_out;

  // Workspace layout
  const size_t cnt_bytes  = (size_t)N_NODES * sizeof(int);            // 400000
  const size_t rp_bytes   = (size_t)(N_NODES + 1) * sizeof(int);      // 400004
  const size_t off_sorted = ((cnt_bytes + rp_bytes + 15) / 16) * 16;  // 800016
  const size_t sorted_b   = (size_t)N_EDGES * 8;                      // 25.6 MB
  const size_t off_xb     = off_sorted + sorted_b;
  const size_t xb_b       = (size_t)N_NODES * D * 2;                  // 51.2 MB
  const size_t off_sup    = off_xb + xb_b;
  const size_t sup_b      = (size_t)(N_NODES + 32) * D * 2;           // padded M
  const size_t off_wt     = off_sup + sup_b;
  const size_t wt_b       = (size_t)D * D * 2;
  const size_t need_A     = off_wt + wt_b;                            // ~129 MB
  const size_t need_B     = off_sorted + sorted_b;                    // ~26.4 MB

  if (ws_size >= need_A) {
    int*    cnt     = (int*)d_ws;
    int*    row_ptr = (int*)((char*)d_ws + cnt_bytes);
    int2*   sorted  = (int2*)((char*)d_ws + off_sorted);
    ushort* xb      = (ushort*)((char*)d_ws + off_xb);
    ushort* sup     = (ushort*)((char*)d_ws + off_sup);
    ushort* wt      = (ushort*)((char*)d_ws + off_wt);

    hipMemsetAsync(cnt, 0, cnt_bytes, stream);
    convert_x<<<N_NODES * D / 4 / 256, 256, 0, stream>>>((const float4*)x, xb);
    convert_wt<<<D, 64, 0, stream>>>(W, wt);
    hist_kernel<<<2048, 256, 0, stream>>>(erow, cnt);
    scan_kernel<<<1, 1024, 0, stream>>>(cnt, row_ptr);
    sort_scatter_kernel<<<(N_EDGES + 255) / 256, 256, 0, stream>>>(
        erow, ecol, eval_, row_ptr, cnt, sorted);
    row_accum_bf16<<<N_NODES / 4, 256, 0, stream>>>(xb, sorted, row_ptr, sup);
    mfma_gemm_relu<<<(N_NODES + 63) / 64, 256, 0, stream>>>(sup, wt, out);
  } else if (ws_size >= need_B) {
    int*  cnt     = (int*)d_ws;
    int*  row_ptr = (int*)((char*)d_ws + cnt_bytes);
    int2* sorted  = (int2*)((char*)d_ws + off_sorted);

    hipMemsetAsync(cnt, 0, cnt_bytes, stream);
    hist_kernel<<<2048, 256, 0, stream>>>(erow, cnt);
    scan_kernel<<<1, 1024, 0, stream>>>(cnt, row_ptr);
    sort_scatter_kernel<<<(N_EDGES + 255) / 256, 256, 0, stream>>>(
        erow, ecol, eval_, row_ptr, cnt, sorted);
    row_accum_kernel<<<(N_NODES * 64 + 255) / 256, 256, 0, stream>>>(
        x, sorted, row_ptr, out);
    gemm_relu_inplace<<<N_NODES / 32, 256, 0, stream>>>(W, out);
  } else {
    hipMemsetAsync(out, 0, (size_t)N_NODES * D * sizeof(float), stream);
    const int blocks = 2048;
    const int nwaves = blocks * (256 / 64);
    scatter_kernel<<<blocks, 256, 0, stream>>>(x, erow, ecol, eval_, out, nwaves);
    gemm_relu_inplace<<<N_NODES / 32, 256, 0, stream>>>(W, out);
  }
}

// Round 4
// 680.519 us; speedup vs baseline: 15.8332x; 1.3272x over previous
//
#include <hip/hip_runtime.h>

#define N_NODES 100000
#define N_EDGES 3200000
#define D 256

typedef __attribute__((ext_vector_type(8))) short short8;
typedef __attribute__((ext_vector_type(8))) unsigned short ushort8;
typedef __attribute__((ext_vector_type(4))) float f32x4;

static __device__ __forceinline__ unsigned short f2bf(float f) {
  unsigned u = __float_as_uint(f);
  u += 0x7FFF + ((u >> 16) & 1);  // round-to-nearest-even
  return (unsigned short)(u >> 16);
}
static __device__ __forceinline__ float bf2f(unsigned short h) {
  return __uint_as_float(((unsigned)h) << 16);
}

// ===========================================================================
// CSR build
// ===========================================================================
// K1: histogram, 4 edges/thread (N_EDGES % 1024 == 0).
__global__ __launch_bounds__(256) void hist4_kernel(
    const int4* __restrict__ erow4, int* __restrict__ cnt) {
  int i = blockIdx.x * 256 + threadIdx.x;
  int4 e = erow4[i];
  atomicAdd(&cnt[e.x], 1);
  atomicAdd(&cnt[e.y], 1);
  atomicAdd(&cnt[e.z], 1);
  atomicAdd(&cnt[e.w], 1);
}

// K2a: per-1024-block exclusive scan; block sums out.
__global__ __launch_bounds__(1024) void scan1_kernel(
    const int* __restrict__ cnt, int* __restrict__ row_ptr,
    int* __restrict__ bsum) {
  __shared__ int s[1024];
  int gid = blockIdx.x * 1024 + threadIdx.x;
  int v = (gid < N_NODES) ? cnt[gid] : 0;
  s[threadIdx.x] = v;
  __syncthreads();
  for (int off = 1; off < 1024; off <<= 1) {
    int t = (threadIdx.x >= off) ? s[threadIdx.x - off] : 0;
    __syncthreads();
    s[threadIdx.x] += t;
    __syncthreads();
  }
  if (gid < N_NODES) row_ptr[gid] = s[threadIdx.x] - v;  // block-local exclusive
  if (threadIdx.x == 1023) bsum[blockIdx.x] = s[1023];
}

// K2b: exclusive scan of the 98 block sums (in place); writes grand total.
__global__ __launch_bounds__(128) void scan2_kernel(
    int* __restrict__ bsum, int* __restrict__ row_ptr, int nblk) {
  __shared__ int s[128];
  int v = (threadIdx.x < nblk) ? bsum[threadIdx.x] : 0;
  s[threadIdx.x] = v;
  __syncthreads();
  for (int off = 1; off < 128; off <<= 1) {
    int t = (threadIdx.x >= off) ? s[threadIdx.x - off] : 0;
    __syncthreads();
    s[threadIdx.x] += t;
    __syncthreads();
  }
  if (threadIdx.x < nblk) bsum[threadIdx.x] = s[threadIdx.x] - v;
  if (threadIdx.x == 127) row_ptr[N_NODES] = s[127];
}

// K2c: add block offsets; init cursor = row start.
__global__ __launch_bounds__(1024) void scan3_kernel(
    int* __restrict__ row_ptr, const int* __restrict__ bsum,
    int* __restrict__ cursor) {
  int gid = blockIdx.x * 1024 + threadIdx.x;
  if (gid < N_NODES) {
    int rp = row_ptr[gid] + bsum[blockIdx.x];
    row_ptr[gid] = rp;
    cursor[gid] = rp;
  }
}

// K3: scatter edges row-sorted, 2 edges/thread (N_EDGES % 512 == 0).
__global__ __launch_bounds__(256) void sort_scatter2_kernel(
    const int2* __restrict__ erow2, const int2* __restrict__ ecol2,
    const float2* __restrict__ eval2, int* __restrict__ cursor,
    int2* __restrict__ sorted) {
  int i = blockIdx.x * 256 + threadIdx.x;
  int2 r = erow2[i];
  int2 c = ecol2[i];
  float2 v = eval2[i];
  int p0 = atomicAdd(&cursor[r.x], 1);
  int p1 = atomicAdd(&cursor[r.y], 1);
  sorted[p0] = make_int2(c.x, __float_as_int(v.x));
  sorted[p1] = make_int2(c.y, __float_as_int(v.y));
}

// ===========================================================================
// Y = bf16( f32(X) @ bf16(W) )   [N_NODES x D], Y padded to N_NODES+64 rows.
// Block: 4 waves, tile 64(M) x 256(N). Verified mfma_f32_16x16x32_bf16 layout.
// ===========================================================================
__global__ __launch_bounds__(64) void convert_wt(
    const float* __restrict__ W, ushort* __restrict__ wt) {
  int n = blockIdx.x;
  int k0 = threadIdx.x * 4;
  ushort4 o;
  o.x = f2bf(W[(size_t)(k0 + 0) * D + n]);
  o.y = f2bf(W[(size_t)(k0 + 1) * D + n]);
  o.z = f2bf(W[(size_t)(k0 + 2) * D + n]);
  o.w = f2bf(W[(size_t)(k0 + 3) * D + n]);
  *(ushort4*)(wt + (size_t)n * D + k0) = o;
}

__global__ __launch_bounds__(256) void gemm_xw_bf16(
    const float* __restrict__ x, const ushort* __restrict__ wt,
    ushort* __restrict__ Y) {
  const int lane = threadIdx.x & 63;
  const int wave = threadIdx.x >> 6;
  const int m0 = blockIdx.x * 64;
  const int n0 = wave * 64;
  const int lrow = lane & 15;
  const int kch = (lane >> 4) * 8;

  f32x4 acc[4][4];
  #pragma unroll
  for (int i = 0; i < 4; ++i)
    #pragma unroll
    for (int j = 0; j < 4; ++j) acc[i][j] = (f32x4){0.f, 0.f, 0.f, 0.f};

  int arow[4];
  #pragma unroll
  for (int i = 0; i < 4; ++i) {
    int rr = m0 + i * 16 + lrow;
    arow[i] = rr < N_NODES ? rr : N_NODES - 1;  // clamp: x is exact-sized input
  }
  const ushort* sb = wt + (size_t)(n0 + lrow) * D + kch;

  #pragma unroll
  for (int ks = 0; ks < 8; ++ks) {
    short8 a[4], b[4];
    #pragma unroll
    for (int i = 0; i < 4; ++i) {
      const float* ap = x + (size_t)arow[i] * D + kch + ks * 32;
      float4 f0 = *(const float4*)ap;
      float4 f1 = *(const float4*)(ap + 4);
      short8 av;
      av[0] = (short)f2bf(f0.x); av[1] = (short)f2bf(f0.y);
      av[2] = (short)f2bf(f0.z); av[3] = (short)f2bf(f0.w);
      av[4] = (short)f2bf(f1.x); av[5] = (short)f2bf(f1.y);
      av[6] = (short)f2bf(f1.z); av[7] = (short)f2bf(f1.w);
      a[i] = av;
      b[i] = *(const short8*)(sb + (size_t)i * 16 * D + ks * 32);
    }
    #pragma unroll
    for (int mi = 0; mi < 4; ++mi)
      #pragma unroll
      for (int ni = 0; ni < 4; ++ni)
        acc[mi][ni] = __builtin_amdgcn_mfma_f32_16x16x32_bf16(
            a[mi], b[ni], acc[mi][ni], 0, 0, 0);
  }

  #pragma unroll
  for (int mi = 0; mi < 4; ++mi) {
    int rbase = m0 + mi * 16 + (lane >> 4) * 4;
    #pragma unroll
    for (int ni = 0; ni < 4; ++ni) {
      int col = n0 + ni * 16 + lrow;
      #pragma unroll
      for (int j = 0; j < 4; ++j)
        Y[(size_t)(rbase + j) * D + col] = f2bf(acc[mi][ni][j]);  // padded rows
    }
  }
}

// ===========================================================================
// out = relu(P @ Y): one wave per row; 32 lanes x 16B gathers; 2 edges in
// parallel across the two half-waves; 8-edge unroll; shfl_xor(32) reduce.
// ===========================================================================
__global__ __launch_bounds__(256) void row_accum_relu(
    const ushort* __restrict__ Y, const int2* __restrict__ sorted,
    const int* __restrict__ row_ptr, float* __restrict__ out) {
  const int lane = threadIdx.x & 63;
  const int l5 = lane & 31;
  const int sub = lane >> 5;
  int r = (int)((blockIdx.x << 2) + (threadIdx.x >> 6));
  r = __builtin_amdgcn_readfirstlane(r);
  if (r >= N_NODES) return;
  int beg = row_ptr[r];
  int end = row_ptr[r + 1];
  const int eo = l5 * 8;  // element offset; 16B per lane

  float acc[8] = {0.f, 0.f, 0.f, 0.f, 0.f, 0.f, 0.f, 0.f};

  int p = beg;
  if ((p & 1) && p < end) {  // peel to even alignment; sub0 only
    int2 e = sorted[p];
    int c = sub ? 0 : e.x;
    float v = sub ? 0.f : __int_as_float(e.y);
    ushort8 g = *(const ushort8*)(Y + (size_t)c * D + eo);
    #pragma unroll
    for (int i = 0; i < 8; ++i) acc[i] = fmaf(v, bf2f(g[i]), acc[i]);
    ++p;
  }
  for (; p + 8 <= end; p += 8) {
    int4 q0 = *(const int4*)(sorted + p);
    int4 q1 = *(const int4*)(sorted + p + 2);
    int4 q2 = *(const int4*)(sorted + p + 4);
    int4 q3 = *(const int4*)(sorted + p + 6);
    int c0 = sub ? q0.z : q0.x;
    int c1 = sub ? q1.z : q1.x;
    int c2 = sub ? q2.z : q2.x;
    int c3 = sub ? q3.z : q3.x;
    ushort8 g0 = *(const ushort8*)(Y + (size_t)c0 * D + eo);
    ushort8 g1 = *(const ushort8*)(Y + (size_t)c1 * D + eo);
    ushort8 g2 = *(const ushort8*)(Y + (size_t)c2 * D + eo);
    ushort8 g3 = *(const ushort8*)(Y + (size_t)c3 * D + eo);
    float v0 = __int_as_float(sub ? q0.w : q0.y);
    float v1 = __int_as_float(sub ? q1.w : q1.y);
    float v2 = __int_as_float(sub ? q2.w : q2.y);
    float v3 = __int_as_float(sub ? q3.w : q3.y);
    #pragma unroll
    for (int i = 0; i < 8; ++i) acc[i] = fmaf(v0, bf2f(g0[i]), acc[i]);
    #pragma unroll
    for (int i = 0; i < 8; ++i) acc[i] = fmaf(v1, bf2f(g1[i]), acc[i]);
    #pragma unroll
    for (int i = 0; i < 8; ++i) acc[i] = fmaf(v2, bf2f(g2[i]), acc[i]);
    #pragma unroll
    for (int i = 0; i < 8; ++i) acc[i] = fmaf(v3, bf2f(g3[i]), acc[i]);
  }
  for (; p < end; p += 2) {  // tail; p even; sorted has +2 pad entries
    int4 q = *(const int4*)(sorted + p);
    bool valid = (p + sub) < end;
    int c = valid ? (sub ? q.z : q.x) : 0;
    float v = valid ? __int_as_float(sub ? q.w : q.y) : 0.f;
    ushort8 g = *(const ushort8*)(Y + (size_t)c * D + eo);
    #pragma unroll
    for (int i = 0; i < 8; ++i) acc[i] = fmaf(v, bf2f(g[i]), acc[i]);
  }

  #pragma unroll
  for (int i = 0; i < 8; ++i) acc[i] += __shfl_xor(acc[i], 32, 64);

  float4 o;
  if (sub == 0) o = make_float4(acc[0], acc[1], acc[2], acc[3]);
  else          o = make_float4(acc[4], acc[5], acc[6], acc[7]);
  o.x = fmaxf(o.x, 0.f); o.y = fmaxf(o.y, 0.f);
  o.z = fmaxf(o.z, 0.f); o.w = fmaxf(o.w, 0.f);
  *(float4*)(out + (size_t)r * D + eo + sub * 4) = o;
}

// ===========================================================================
// Fallback path B (round-2, proven): f32 CSR accumulate + f32 VALU GEMM.
// ===========================================================================
__global__ __launch_bounds__(256) void hist_kernel(
    const int* __restrict__ erow, int* __restrict__ cnt) {
  int stride = gridDim.x * blockDim.x;
  for (int e = blockIdx.x * blockDim.x + threadIdx.x; e < N_EDGES; e += stride)
    atomicAdd(&cnt[erow[e]], 1);
}

__global__ __launch_bounds__(1024) void scan_kernel(
    int* __restrict__ cnt, int* __restrict__ row_ptr) {
  __shared__ int partial[1024];
  const int T = 1024;
  const int per = (N_NODES + T - 1) / T;
  int tid = threadIdx.x;
  int base = tid * per;
  int sum = 0;
  for (int i = 0; i < per; ++i) {
    int idx = base + i;
    if (idx < N_NODES) sum += cnt[idx];
  }
  partial[tid] = sum;
  __syncthreads();
  for (int off = 1; off < T; off <<= 1) {
    int v = (tid >= off) ? partial[tid - off] : 0;
    __syncthreads();
    partial[tid] += v;
    __syncthreads();
  }
  int run = (tid == 0) ? 0 : partial[tid - 1];
  for (int i = 0; i < per; ++i) {
    int idx = base + i;
    if (idx < N_NODES) {
      row_ptr[idx] = run;
      run += cnt[idx];
      cnt[idx] = 0;
    }
  }
  if (tid == T - 1) row_ptr[N_NODES] = run;
}

__global__ __launch_bounds__(256) void sort_scatter_kernel(
    const int* __restrict__ erow, const int* __restrict__ ecol,
    const float* __restrict__ eval_, const int* __restrict__ row_ptr,
    int* __restrict__ cursor, int2* __restrict__ sorted) {
  int e = blockIdx.x * blockDim.x + threadIdx.x;
  if (e >= N_EDGES) return;
  int r = erow[e];
  int pos = row_ptr[r] + atomicAdd(&cursor[r], 1);
  sorted[pos] = make_int2(ecol[e], __float_as_int(eval_[e]));
}

__global__ __launch_bounds__(256) void row_accum_kernel(
    const float* __restrict__ x, const int2* __restrict__ sorted,
    const int* __restrict__ row_ptr, float* __restrict__ support) {
  int lane = threadIdx.x & 63;
  int r = (int)((blockIdx.x * blockDim.x + threadIdx.x) >> 6);
  if (r >= N_NODES) return;
  int beg = row_ptr[r];
  int end = row_ptr[r + 1];
  const float4* __restrict__ x4 = (const float4*)x;
  float4 acc = make_float4(0.f, 0.f, 0.f, 0.f);
  int p = beg;
  for (; p + 1 < end; p += 2) {
    int2 cv0 = sorted[p];
    int2 cv1 = sorted[p + 1];
    float4 xv0 = x4[(size_t)cv0.x * 64 + lane];
    float4 xv1 = x4[(size_t)cv1.x * 64 + lane];
    float v0 = __int_as_float(cv0.y);
    float v1 = __int_as_float(cv1.y);
    acc.x = fmaf(v0, xv0.x, acc.x); acc.y = fmaf(v0, xv0.y, acc.y);
    acc.z = fmaf(v0, xv0.z, acc.z); acc.w = fmaf(v0, xv0.w, acc.w);
    acc.x = fmaf(v1, xv1.x, acc.x); acc.y = fmaf(v1, xv1.y, acc.y);
    acc.z = fmaf(v1, xv1.z, acc.z); acc.w = fmaf(v1, xv1.w, acc.w);
  }
  if (p < end) {
    int2 cv = sorted[p];
    float v = __int_as_float(cv.y);
    float4 xv = x4[(size_t)cv.x * 64 + lane];
    acc.x = fmaf(v, xv.x, acc.x); acc.y = fmaf(v, xv.y, acc.y);
    acc.z = fmaf(v, xv.z, acc.z); acc.w = fmaf(v, xv.w, acc.w);
  }
  ((float4*)support)[(size_t)r * 64 + lane] = acc;
}

__global__ __launch_bounds__(256) void scatter_kernel(
    const float* __restrict__ x, const int* __restrict__ erow,
    const int* __restrict__ ecol, const float* __restrict__ eval_,
    float* __restrict__ support, int nwaves) {
  int lane = threadIdx.x & 63;
  int wave = __builtin_amdgcn_readfirstlane(
      (int)((blockIdx.x * blockDim.x + threadIdx.x) >> 6));
  for (int e = wave; e < N_EDGES; e += nwaves) {
    int r = erow[e];
    int c = ecol[e];
    float v = eval_[e];
    float4 xv = ((const float4*)(x + (size_t)c * D))[lane];
    float* dst = support + (size_t)r * D + lane * 4;
    atomicAdd(dst + 0, v * xv.x);
    atomicAdd(dst + 1, v * xv.y);
    atomicAdd(dst + 2, v * xv.z);
    atomicAdd(dst + 3, v * xv.w);
  }
}

__global__ __launch_bounds__(256) void gemm_relu_inplace(
    const float* __restrict__ W, float* __restrict__ io) {
  __shared__ float s[32][D];
  const int tid = threadIdx.x;
  const int row0 = blockIdx.x * 32;
  {
    const float4* src = (const float4*)(io + (size_t)row0 * D);
    float4* sd = (float4*)&s[0][0];
    #pragma unroll
    for (int t = 0; t < 8; ++t) sd[tid + t * 256] = src[tid + t * 256];
  }
  __syncthreads();
  const int j0 = (tid & 63) * 4;
  const int i0 = (tid >> 6) * 8;
  float acc[8][4];
  #pragma unroll
  for (int i = 0; i < 8; ++i)
    for (int q = 0; q < 4; ++q) acc[i][q] = 0.f;
  #pragma unroll 4
  for (int k = 0; k < D; ++k) {
    float4 w4 = *(const float4*)(W + (size_t)k * D + j0);
    #pragma unroll
    for (int i = 0; i < 8; ++i) {
      float sv = s[i0 + i][k];
      acc[i][0] = fmaf(sv, w4.x, acc[i][0]);
      acc[i][1] = fmaf(sv, w4.y, acc[i][1]);
      acc[i][2] = fmaf(sv, w4.z, acc[i][2]);
      acc[i][3] = fmaf(sv, w4.w, acc[i][3]);
    }
  }
  #pragma unroll
  for (int i = 0; i < 8; ++i) {
    float4 o;
    o.x = fmaxf(acc[i][0], 0.f);
    o.y = fmaxf(acc[i][1], 0.f);
    o.z = fmaxf(acc[i][2], 0.f);
    o.w = fmaxf(acc[i][3], 0.f);
    *(float4*)(io + (size_t)(row0 + i0 + i) * D + j0) = o;
  }
}

extern "C" void kernel_launch(void* const* d_in, const int* in_sizes, int n_in,
                              void* d_out, int out_size, void* d_ws, size_t ws_size,
                              hipStream_t stream) {
  const float* x     = (const float*)d_in[0];
  const int*   erow  = (const int*)d_in[1];
  const int*   ecol  = (const int*)d_in[2];
  const float* eval_ = (const float*)d_in[3];
  const float* W     = (const float*)d_in[4];
  float* out = (float*)d_out;

  // Workspace layout (path A)
  const size_t cnt_bytes  = (size_t)N_NODES * sizeof(int);            // 400000
  const size_t rp_bytes   = (size_t)(N_NODES + 1) * sizeof(int);
  const size_t off_sorted = ((cnt_bytes + rp_bytes + 15) / 16) * 16;  // 800016
  const size_t sorted_b   = (size_t)(N_EDGES + 2) * 8;                // +pad
  const size_t off_Y      = off_sorted + sorted_b;
  const size_t Y_b        = (size_t)(N_NODES + 64) * D * 2;           // padded M
  const size_t off_wt     = off_Y + Y_b;
  const size_t wt_b       = (size_t)D * D * 2;
  const size_t off_bsum   = off_wt + wt_b;
  const size_t bsum_b     = 128 * sizeof(int);
  const size_t need_A     = off_bsum + bsum_b;                        // ~77.8 MB
  const size_t need_B     = off_sorted + sorted_b;                    // ~26.4 MB

  const int SCAN_BLKS = (N_NODES + 1023) / 1024;  // 98

  if (ws_size >= need_A) {
    int*    cnt     = (int*)d_ws;
    int*    row_ptr = (int*)((char*)d_ws + cnt_bytes);
    int2*   sorted  = (int2*)((char*)d_ws + off_sorted);
    ushort* Y       = (ushort*)((char*)d_ws + off_Y);
    ushort* wt      = (ushort*)((char*)d_ws + off_wt);
    int*    bsum    = (int*)((char*)d_ws + off_bsum);

    hipMemsetAsync(cnt, 0, cnt_bytes, stream);
    convert_wt<<<D, 64, 0, stream>>>(W, wt);
    hist4_kernel<<<N_EDGES / 1024, 256, 0, stream>>>((const int4*)erow, cnt);
    scan1_kernel<<<SCAN_BLKS, 1024, 0, stream>>>(cnt, row_ptr, bsum);
    scan2_kernel<<<1, 128, 0, stream>>>(bsum, row_ptr, SCAN_BLKS);
    scan3_kernel<<<SCAN_BLKS, 1024, 0, stream>>>(row_ptr, bsum, cnt);
    sort_scatter2_kernel<<<N_EDGES / 512, 256, 0, stream>>>(
        (const int2*)erow, (const int2*)ecol, (const float2*)eval_, cnt, sorted);
    gemm_xw_bf16<<<(N_NODES + 63) / 64, 256, 0, stream>>>(x, wt, Y);
    row_accum_relu<<<(N_NODES + 3) / 4, 256, 0, stream>>>(Y, sorted, row_ptr, out);
  } else if (ws_size >= need_B) {
    int*  cnt     = (int*)d_ws;
    int*  row_ptr = (int*)((char*)d_ws + cnt_bytes);
    int2* sorted  = (int2*)((char*)d_ws + off_sorted);

    hipMemsetAsync(cnt, 0, cnt_bytes, stream);
    hist_kernel<<<2048, 256, 0, stream>>>(erow, cnt);
    scan_kernel<<<1, 1024, 0, stream>>>(cnt, row_ptr);
    sort_scatter_kernel<<<(N_EDGES + 255) / 256, 256, 0, stream>>>(
        erow, ecol, eval_, row_ptr, cnt, sorted);
    row_accum_kernel<<<(N_NODES * 64 + 255) / 256, 256, 0, stream>>>(
        x, sorted, row_ptr, out);
    gemm_relu_inplace<<<N_NODES / 32, 256, 0, stream>>>(W, out);
  } else {
    hipMemsetAsync(out, 0, (size_t)N_NODES * D * sizeof(float), stream);
    const int blocks = 2048;
    const int nwaves = blocks * (256 / 64);
    scatter_kernel<<<blocks, 256, 0, stream>>>(x, erow, ecol, eval_, out, nwaves);
    gemm_relu_inplace<<<N_NODES / 32, 256, 0, stream>>>(W, out);
  }
}